// Round 5
// baseline (3911.936 us; speedup 1.0000x reference)
//
#include <hip/hip_runtime.h>
#include <math.h>

typedef unsigned short ushortT;
typedef __attribute__((ext_vector_type(4))) float f32x4;
typedef __attribute__((ext_vector_type(4))) unsigned int u32x4;
typedef __attribute__((ext_vector_type(4))) unsigned short u16x4;
typedef __attribute__((ext_vector_type(4))) int i32x4;

namespace {
constexpr int S = 256;
constexpr int H = 768;
constexpr int NLAY = 12;
constexpr int NHD = 12;
constexpr int FF = 3072;
constexpr int LBL = 9;
constexpr int DH = 64;
constexpr int BATCH = 32;
constexpr int TOKENS = BATCH * S;      // 8192
constexpr float SCALE = 0.125f;        // 1/sqrt(64)
constexpr int QKVN = 3 * H;            // 2304

// workspace layout (float-slot units)
constexpr size_t H_OFF   = 0;                          // h f32 [8192*768]
constexpr size_t HB_OFF  = H_OFF + (size_t)TOKENS*H;   // h bf16 (half slots)
constexpr size_t QB_OFF  = HB_OFF + (size_t)TOKENS*H/2;  // q / ctx / ff2out bf16
constexpr size_t KB_OFF  = QB_OFF + (size_t)TOKENS*H/2;  // k / attn-out bf16
constexpr size_t VT_OFF  = KB_OFF + (size_t)TOKENS*H/2;  // v^T bf16 [B*NH*DH][S]
constexpr size_t BIG_OFF = VT_OFF + (size_t)TOKENS*H/2;  // scores bf16 == ff1 bf16
constexpr size_t WTQ_OFF = BIG_OFF + (size_t)TOKENS*FF/2;  // Wq^T,Wk^T,Wv^T contiguous
constexpr size_t WTO_OFF = WTQ_OFF + 3*(size_t)H*H/2;
constexpr size_t WT1_OFF = WTO_OFF + (size_t)H*H/2;      // W1^T [3072][768]
constexpr size_t WT2_OFF = WT1_OFF + (size_t)H*FF/2;     // W2^T [768][3072]
constexpr size_t EM_OFF  = WT2_OFF + (size_t)H*FF/2;
constexpr size_t PART_OFF= EM_OFF + (size_t)TOKENS*LBL;
constexpr size_t BQKV_OFF= PART_OFF + 64;                // packed qkv bias [12][2304]
constexpr size_t WS_FLOATS = BQKV_OFF + (size_t)NLAY*QKVN;
}

__device__ __forceinline__ ushortT f2bf(float x) {
    unsigned u = __builtin_bit_cast(unsigned, x);
    u += 0x7fffu + ((u >> 16) & 1u);
    return (ushortT)(u >> 16);
}
__device__ __forceinline__ float bf2f(ushortT h) {
    unsigned u = ((unsigned)h) << 16;
    return __builtin_bit_cast(float, u);
}

__device__ inline float gelu_tanh(float x) {
    float x3 = x * x * x;
    return 0.5f * x * (1.0f + tanhf(0.7978845608028654f * (x + 0.044715f * x3)));
}

__device__ __forceinline__ float exp2i(float x) {
    float r; asm("v_exp_f32 %0, %1" : "=v"(r) : "v"(x)); return r;
}
__device__ __forceinline__ float log2i(float x) {
    float r; asm("v_log_f32 %0, %1" : "=v"(r) : "v"(x)); return r;
}

__device__ __forceinline__ void mfma_bf16(f32x4& c, const u32x4& a, const u32x4& b) {
    asm("v_mfma_f32_16x16x32_bf16 %0, %1, %2, %0" : "+v"(c) : "v"(a), "v"(b));
}

__device__ __forceinline__ void gload_lds16(const ushortT* g, ushortT* l) {
    __builtin_amdgcn_global_load_lds(
        (const __attribute__((address_space(1))) unsigned int*)g,
        (__attribute__((address_space(3))) unsigned int*)l,
        16, 0, 0);
}

// =====================================================================
// 256x256 8-phase bf16 GEMM — DEEP pipeline (R5):
// Loads for tile t+1 are issued as: 6 loads (B rounds 0-3 + A rows 0-63,
// 128-191) at ph3 of tile t-1 (those LDS regions of buffer (t+1)&1 were
// last read at ph2 of t-1, barrier-protected), and 2 loads (A rows
// 64-127, 192-255) at ph0 of tile t. Waits: vmcnt(8) at ph0 (releases
// the 6-group issued ~5 phases earlier) and vmcnt(8) at ph1 (releases
// the 2-group issued ~5 phases earlier). Up to 14 loads in flight; never
// drains below 8 in the main loop. BK=64, 8 waves (2Mx4N), 128 KiB LDS,
// XOR swizzle slot^= row&7 on both write-source and read.
// MODE: 0 bias bf16 | 1 bias+gelu bf16 | 5 fused-QKV routing
// =====================================================================
template<int MODE>
__global__ __launch_bounds__(512, 2) void gemm256(
    const ushortT* __restrict__ A, int lda,
    const ushortT* __restrict__ Bt, int ldb,
    const float* __restrict__ bias,
    void* __restrict__ Cv, int ldc, int K, int gridN)
{
    __shared__ __align__(16) ushortT sh[65536];   // 128 KiB
    const int tid = threadIdx.x;
    const int wave = tid >> 6, lane = tid & 63;
    const int wm = wave >> 2, wn = wave & 3;
    const int rl = lane & 15, kg = lane >> 4, r7 = lane & 7;

    // XCD-aware swizzle (grid divisible by 8)
    const int nwg = gridDim.x;
    const int cpx = nwg >> 3;
    const int wg = (blockIdx.x & 7) * cpx + (blockIdx.x >> 3);
    const int by = wg / gridN, bx = wg - by * gridN;

    const ushortT* Ab = A + (size_t)by * 256 * lda;
    const ushortT* Bb = Bt + (size_t)bx * 256 * ldb;

    const int kxor8 = ((tid & 7) ^ ((tid >> 3) & 7)) * 8;   // swizzled global k-off
    const int trow = tid >> 3;                               // 0..63 row within round
    const int aoff = (wm * 128 + rl) * 64;
    const int boff = (wn * 64 + rl) * 64;
    const int koff0 = (kg ^ r7) * 8;          // ks=0 swizzled LDS k-off (elems)
    const int koff1 = ((4 | kg) ^ r7) * 8;    // ks=1

    f32x4 acc[8][4];
#pragma unroll
    for (int i = 0; i < 8; ++i)
#pragma unroll
        for (int j = 0; j < 4; ++j) acc[i][j] = (f32x4){0.f, 0.f, 0.f, 0.f};

    const int NT = K >> 6;

#define STAGE_B(RR, KT, NB)                                                     \
    gload_lds16(Bb + (size_t)((RR) * 64 + trow) * ldb + (KT) * 64 + kxor8,      \
                sh + 32768 + (NB) * 16384 + (RR) * 4096 + wave * 512)
#define STAGE_A(ROWBASE, KT, NB)                                                \
    gload_lds16(Ab + (size_t)((ROWBASE) + trow) * lda + (KT) * 64 + kxor8,      \
                sh + (NB) * 16384 + (ROWBASE) * 64 + wave * 512)
#define STAGE6(KT, NB)                                                          \
    STAGE_B(0, KT, NB); STAGE_B(1, KT, NB); STAGE_B(2, KT, NB);                 \
    STAGE_B(3, KT, NB); STAGE_A(0, KT, NB); STAGE_A(128, KT, NB)
#define STAGE2(KT, NB)                                                          \
    STAGE_A(64, KT, NB); STAGE_A(192, KT, NB)
#define LDA_Q(Q, KOFF)                                                          \
    a[0] = *(const u32x4*)(As_ + aoff + (Q) * 4096 +    0 + (KOFF));            \
    a[1] = *(const u32x4*)(As_ + aoff + (Q) * 4096 + 1024 + (KOFF));            \
    a[2] = *(const u32x4*)(As_ + aoff + (Q) * 4096 + 2048 + (KOFF));            \
    a[3] = *(const u32x4*)(As_ + aoff + (Q) * 4096 + 3072 + (KOFF));
#define LDB_(KOFF)                                                              \
    b[0] = *(const u32x4*)(Bs_ + boff +    0 + (KOFF));                         \
    b[1] = *(const u32x4*)(Bs_ + boff + 1024 + (KOFF));                         \
    b[2] = *(const u32x4*)(Bs_ + boff + 2048 + (KOFF));                         \
    b[3] = *(const u32x4*)(Bs_ + boff + 3072 + (KOFF));
#define MFMA_Q(Q)                                                               \
    _Pragma("unroll") for (int mf = 0; mf < 4; ++mf)                            \
    _Pragma("unroll") for (int nf = 0; nf < 4; ++nf)                            \
        mfma_bf16(acc[(Q) * 4 + mf][nf], a[mf], b[nf]);
#define VM8    asm volatile("s_waitcnt vmcnt(8)" ::: "memory")
#define VM0    asm volatile("s_waitcnt vmcnt(0)" ::: "memory")
#define LG0    asm volatile("s_waitcnt lgkmcnt(0)" ::: "memory")
#define SBAR   __builtin_amdgcn_s_barrier()
#define SCB    __builtin_amdgcn_sched_barrier(0)

    // prologue (FIFO order matters): 6(t0)->buf0, 2(t0)->buf0, 6(t1)->buf1
    STAGE6(0, 0);
    STAGE2(0, 0);
    {
        const int t1 = (NT > 1) ? 1 : 0;
        STAGE6(t1, 1);
    }

    u32x4 a[4], b[4];
    for (int kt = 0; kt < NT; ++kt) {
        const int cur = kt & 1, nb = cur ^ 1;
        const int nx1 = (kt + 1 < NT) ? kt + 1 : kt;   // 2-group source (->nb)
        const int nx2 = (kt + 2 < NT) ? kt + 2 : kt;   // 6-group source (->cur)
        const ushortT* As_ = sh + cur * 16384;
        const ushortT* Bs_ = sh + 32768 + cur * 16384;

        // ---- phase 0: q=0, ks=0 (needs B + A rows 0-63/128-191 of tile kt) ----
        VM8; SBAR; SCB;
        LDA_Q(0, koff0); LDB_(koff0);
        STAGE2(nx1, nb);                  // A hi-half of tile kt+1
        LG0; SCB;
        __builtin_amdgcn_s_setprio(1);
        MFMA_Q(0);
        __builtin_amdgcn_s_setprio(0);

        // ---- phase 1: q=1, ks=0 (needs A rows 64-127/192-255 of tile kt) ----
        VM8; SBAR; SCB;
        LDA_Q(1, koff0);
        LG0; SCB;
        __builtin_amdgcn_s_setprio(1);
        MFMA_Q(1);
        __builtin_amdgcn_s_setprio(0);

        // ---- phase 2: q=0, ks=1 (last read of B and A-loQ of tile kt) ----
        SBAR; SCB;
        LDA_Q(0, koff1); LDB_(koff1);
        LG0; SCB;
        __builtin_amdgcn_s_setprio(1);
        MFMA_Q(0);
        __builtin_amdgcn_s_setprio(0);

        // ---- phase 3: q=1, ks=1; B + A-loQ regions of buffer `cur` are now
        //      dead (all waves past ph2 via this barrier) -> stage tile kt+2 ----
        SBAR; SCB;
        LDA_Q(1, koff1);
        STAGE6(nx2, cur);
        LG0; SCB;
        __builtin_amdgcn_s_setprio(1);
        MFMA_Q(1);
        __builtin_amdgcn_s_setprio(0);
    }
    VM0;   // drain leftover (clamped) stages before exit

    // epilogue
    ushortT* Ch = (ushortT*)Cv;
#pragma unroll
    for (int nf = 0; nf < 4; ++nf) {
        const int gn = bx * 256 + wn * 64 + nf * 16 + rl;
        const float bv = bias[gn];
#pragma unroll
        for (int mi = 0; mi < 8; ++mi) {
            const int gm = by * 256 + wm * 128 + (mi >> 2) * 64 + (mi & 3) * 16
                         + ((lane >> 4) << 2);
            if constexpr (MODE == 5) {
                const int region = gn / H;
                const int col = gn - region * H;
                if (region < 2) {
                    ushortT* o = (ushortT*)Cv + (size_t)region * TOKENS * H;
#pragma unroll
                    for (int r = 0; r < 4; ++r)
                        o[(size_t)(gm + r) * H + col] = f2bf(acc[mi][nf][r] + bv);
                } else {
                    u16x4 o;
#pragma unroll
                    for (int r = 0; r < 4; ++r) o[r] = f2bf(acc[mi][nf][r] + bv);
                    const int b_ = gm >> 8, s0 = gm & 255;
                    const int h_ = col >> 6, dh = col & 63;
                    *(u16x4*)((ushortT*)Cv + 2 * (size_t)TOKENS * H +
                              (((size_t)(b_ * NHD + h_) * DH + dh) << 8) + s0) = o;
                }
            } else {
#pragma unroll
                for (int r = 0; r < 4; ++r) {
                    float x = acc[mi][nf][r] + bv;
                    if constexpr (MODE == 1) x = gelu_tanh(x);
                    Ch[(size_t)(gm + r) * ldc + gn] = f2bf(x);
                }
            }
        }
    }
#undef STAGE_B
#undef STAGE_A
#undef STAGE6
#undef STAGE2
#undef LDA_Q
#undef LDB_
#undef MFMA_Q
#undef VM8
#undef VM0
#undef LG0
#undef SBAR
#undef SCB
}

// ---------------- bf16 MFMA GEMM, double-buffered 2-phase (128^2) ----------------
// MODE: 0 = bf16 out + bias, 4 = bf16 no bias
template<int WM, int WN, int MODE>
__global__ __launch_bounds__(256) void gemm_mfma(
    const ushortT* __restrict__ A, int lda, long long sAo, long long sAi,
    const ushortT* __restrict__ Bt, int ldb, long long sBo, long long sBi,
    const float* __restrict__ bias,
    void* __restrict__ Cv, int ldc, long long sCo, long long sCi,
    int K, int innerN)
{
    constexpr int BM = WM * 64, BN = WN * 64;
    __shared__ __align__(16) ushortT As[2][BM * 32];
    __shared__ __align__(16) ushortT Bs[2][BN * 32];
    const int tid = threadIdx.x;
    const int wave = tid >> 6, lane = tid & 63;
    const int ob = blockIdx.z / innerN, ib = blockIdx.z - ob * innerN;
    const int bm = blockIdx.y * BM, bn = blockIdx.x * BN;
    const ushortT* Ab = A + ob * sAo + ib * sAi + (size_t)bm * lda;
    const ushortT* Bb = Bt + ob * sBo + ib * sBi + (size_t)bn * ldb;
    const int wm = wave / WN, wn = wave - wm * WN;

    const int lrow = lane >> 2;
    const int lk16 = (lane & 3) * 8;
    const int rl = lane & 15;
    const int kg = (lane >> 4) * 8;

    f32x4 acc[4][4];
#pragma unroll
    for (int i = 0; i < 4; ++i)
#pragma unroll
        for (int j = 0; j < 4; ++j) acc[i][j] = (f32x4){0.f, 0.f, 0.f, 0.f};

    auto stage = [&](int buf, int k0) {
#pragma unroll
        for (int j = 0; j < WM; ++j) {
            int chunk = j * 4 + wave;
            gload_lds16(Ab + (size_t)(chunk * 16 + lrow) * lda + k0 + lk16,
                        &As[buf][chunk * 512]);
        }
#pragma unroll
        for (int j = 0; j < WN; ++j) {
            int chunk = j * 4 + wave;
            gload_lds16(Bb + (size_t)(chunk * 16 + lrow) * ldb + k0 + lk16,
                        &Bs[buf][chunk * 512]);
        }
    };

    stage(0, 0);
    __syncthreads();
    const int nt = K >> 5;
    int cur = 0;
    for (int t = 0; t < nt; ++t) {
        if (t + 1 < nt) stage(cur ^ 1, (t + 1) << 5);
        u32x4 a[4], b[4];
#pragma unroll
        for (int mf = 0; mf < 4; ++mf)
            a[mf] = *(const u32x4*)&As[cur][(wm * 64 + mf * 16 + rl) * 32 + kg];
#pragma unroll
        for (int nf = 0; nf < 4; ++nf)
            b[nf] = *(const u32x4*)&Bs[cur][(wn * 64 + nf * 16 + rl) * 32 + kg];
#pragma unroll
        for (int mf = 0; mf < 4; ++mf)
#pragma unroll
            for (int nf = 0; nf < 4; ++nf)
                mfma_bf16(acc[mf][nf], a[mf], b[nf]);
        __syncthreads();
        cur ^= 1;
    }

    ushortT* Ch = (ushortT*)Cv + ob * sCo + ib * sCi;
#pragma unroll
    for (int nf = 0; nf < 4; ++nf) {
        int gn = bn + wn * 64 + nf * 16 + rl;
        float bv = 0.f;
        if constexpr (MODE == 0) bv = bias[gn];
#pragma unroll
        for (int mf = 0; mf < 4; ++mf) {
            int gm = bm + wm * 64 + mf * 16 + ((lane >> 4) << 2);
#pragma unroll
            for (int r = 0; r < 4; ++r) {
                float x = acc[mf][nf][r] + bv;
                Ch[(size_t)(gm + r) * ldc + gn] = f2bf(x);
            }
        }
    }
}

// ---------------- all 6 weight transposes of one layer, one dispatch ----------------
__global__ __launch_bounds__(256) void transpose_all_k(
    const float* __restrict__ Wq, const float* __restrict__ Wk,
    const float* __restrict__ Wv, const float* __restrict__ Wo,
    const float* __restrict__ W1, const float* __restrict__ W2,
    ushortT* __restrict__ wtqkv, ushortT* __restrict__ wto,
    ushortT* __restrict__ wt1, ushortT* __restrict__ wt2)
{
    int idx = blockIdx.x;
    const float* W; ushortT* WT; int R, C, tr, tc;
    if (idx < 2304) {
        int mat = idx / 576, t = idx - mat * 576;
        tr = t / 24; tc = t - tr * 24; R = 768; C = 768;
        W = mat == 0 ? Wq : mat == 1 ? Wk : mat == 2 ? Wv : Wo;
        WT = mat < 3 ? wtqkv + (size_t)mat * 768 * 768 : wto;
    } else if (idx < 4608) {
        int t = idx - 2304; tr = t / 96; tc = t - tr * 96;
        R = 768; C = 3072; W = W1; WT = wt1;
    } else {
        int t = idx - 4608; tr = t / 24; tc = t - tr * 24;
        R = 3072; C = 768; W = W2; WT = wt2;
    }
    int r0 = tr * 32, c0 = tc * 32;
    __shared__ float tl[32][33];
    int trd = threadIdx.x >> 3;
    int tc4 = (threadIdx.x & 7) * 4;
    const float4 v = *(const float4*)(W + (size_t)(r0 + trd) * C + c0 + tc4);
    tl[trd][tc4 + 0] = v.x; tl[trd][tc4 + 1] = v.y;
    tl[trd][tc4 + 2] = v.z; tl[trd][tc4 + 3] = v.w;
    __syncthreads();
    u16x4 o;
#pragma unroll
    for (int q = 0; q < 4; ++q) o[q] = f2bf(tl[tc4 + q][trd]);
    *(u16x4*)(WT + (size_t)(c0 + trd) * R + r0 + tc4) = o;
}

// ---------------- pack qkv biases -> [NLAY][2304] ----------------
__global__ __launch_bounds__(256) void pack_bias_k(
    const float* __restrict__ bq, const float* __restrict__ bk,
    const float* __restrict__ bv, float* __restrict__ out)
{
    int l = blockIdx.x / 3, r = blockIdx.x - (blockIdx.x / 3) * 3;
    const float* src = r == 0 ? bq : r == 1 ? bk : bv;
#pragma unroll
    for (int j = 0; j < 3; ++j) {
        int d = threadIdx.x + 256 * j;
        out[(size_t)l * QKVN + r * H + d] = src[(size_t)l * H + d];
    }
}

// ---------------- block reduce helper ----------------
__device__ inline void blk_reduce2(float& s, float& ss, float* red) {
#pragma unroll
    for (int m = 32; m; m >>= 1) { s += __shfl_xor(s, m); ss += __shfl_xor(ss, m); }
    int w = threadIdx.x >> 6;
    if ((threadIdx.x & 63) == 0) { red[w] = s; red[4 + w] = ss; }
    __syncthreads();
    s = red[0] + red[1] + red[2] + red[3];
    ss = red[4] + red[5] + red[6] + red[7];
}

// ---------------- embeddings + LN (emit f32 + bf16) ----------------
__global__ __launch_bounds__(256) void embed_ln_k(
    const int* __restrict__ ids, const int* __restrict__ tts,
    const float* __restrict__ wemb, const float* __restrict__ pemb,
    const float* __restrict__ temb, const float* __restrict__ g,
    const float* __restrict__ bp, float* __restrict__ h, ushortT* __restrict__ hb)
{
    int tok = blockIdx.x, tid = threadIdx.x;
    int spos = tok & (S - 1);
    int id = ids[tok], tt = tts[tok];
    const float* wr = wemb + (size_t)id * H;
    const float* pr = pemb + (size_t)spos * H;
    const float* tr = temb + (size_t)tt * H;
    float x[3]; float s = 0.f, ss = 0.f;
#pragma unroll
    for (int j = 0; j < 3; ++j) {
        int d = tid + 256 * j;
        x[j] = wr[d] + pr[d] + tr[d];
        s += x[j]; ss += x[j] * x[j];
    }
    __shared__ float red[8];
    blk_reduce2(s, ss, red);
    float mu = s * (1.f / H);
    float var = ss * (1.f / H) - mu * mu;
    float rs = rsqrtf(var + 1e-12f);
#pragma unroll
    for (int j = 0; j < 3; ++j) {
        int d = tid + 256 * j;
        float y = (x[j] - mu) * rs * g[d] + bp[d];
        h[(size_t)tok * H + d] = y;
        hb[(size_t)tok * H + d] = f2bf(y);
    }
}

// ---------------- residual add (bf16 operand) + LN, in place on h ----------------
__global__ __launch_bounds__(256) void add_ln_k(
    float* __restrict__ h, const ushortT* __restrict__ add,
    const float* __restrict__ g, const float* __restrict__ bp,
    ushortT* __restrict__ hb)
{
    int tok = blockIdx.x, tid = threadIdx.x;
    float x[3]; float s = 0.f, ss = 0.f;
#pragma unroll
    for (int j = 0; j < 3; ++j) {
        int d = tid + 256 * j;
        x[j] = h[(size_t)tok * H + d] + bf2f(add[(size_t)tok * H + d]);
        s += x[j]; ss += x[j] * x[j];
    }
    __shared__ float red[8];
    blk_reduce2(s, ss, red);
    float mu = s * (1.f / H);
    float var = ss * (1.f / H) - mu * mu;
    float rs = rsqrtf(var + 1e-12f);
#pragma unroll
    for (int j = 0; j < 3; ++j) {
        int d = tid + 256 * j;
        float y = (x[j] - mu) * rs * g[d] + bp[d];
        h[(size_t)tok * H + d] = y;
        hb[(size_t)tok * H + d] = f2bf(y);
    }
}

// ---------------- scale + mask + softmax on bf16 scores (in place) ----------------
__global__ __launch_bounds__(256) void attn_softmax_bf16_k(
    ushortT* __restrict__ att, const int* __restrict__ mask)
{
    int blk = blockIdx.x, tid = threadIdx.x;
    int bh = blk >> 4;
    int r0 = (blk & 15) * 16;
    int b = bh / NHD;
    int r = tid >> 4, c0 = (tid & 15) * 16;
    ushortT* rp = att + ((size_t)bh * S + r0 + r) * S;
    const int* mrow = mask + (size_t)b * S;

    u32x4 x0 = *(const u32x4*)(rp + c0);
    u32x4 x1 = *(const u32x4*)(rp + c0 + 8);
    unsigned w[8];
    *(u32x4*)&w[0] = x0; *(u32x4*)&w[4] = x1;
    float v[16];
#pragma unroll
    for (int i = 0; i < 8; ++i) {
        v[2 * i]     = bf2f((ushortT)(w[i] & 0xffffu));
        v[2 * i + 1] = bf2f((ushortT)(w[i] >> 16));
    }
#pragma unroll
    for (int j = 0; j < 16; ++j)
        v[j] = v[j] * SCALE + (mrow[c0 + j] ? 0.f : -1e9f);
    float mx = -1e30f;
#pragma unroll
    for (int j = 0; j < 16; ++j) mx = fmaxf(mx, v[j]);
#pragma unroll
    for (int m = 8; m; m >>= 1) mx = fmaxf(mx, __shfl_xor(mx, m));
    float sum = 0.f;
#pragma unroll
    for (int j = 0; j < 16; ++j) { v[j] = expf(v[j] - mx); sum += v[j]; }
#pragma unroll
    for (int m = 8; m; m >>= 1) sum += __shfl_xor(sum, m);
    float inv = 1.f / sum;
#pragma unroll
    for (int i = 0; i < 8; ++i)
        w[i] = (unsigned)f2bf(v[2 * i] * inv) |
               ((unsigned)f2bf(v[2 * i + 1] * inv) << 16);
    *(u32x4*)(rp + c0) = *(u32x4*)&w[0];
    *(u32x4*)(rp + c0 + 8) = *(u32x4*)&w[4];
}

// ---------------- logits + log_softmax over 9 labels (f32 exact) ----------------
__global__ __launch_bounds__(256) void logits_k(
    const float* __restrict__ h, const float* __restrict__ fcw, float* __restrict__ em)
{
    int tok = blockIdx.x, tid = threadIdx.x;
    float p[LBL];
#pragma unroll
    for (int l = 0; l < LBL; ++l) p[l] = 0.f;
    const float* hr = h + (size_t)tok * H;
#pragma unroll
    for (int j = 0; j < 3; ++j) {
        int d = tid + 256 * j;
        float hv = hr[d];
        const float* fr = fcw + (size_t)d * LBL;
#pragma unroll
        for (int l = 0; l < LBL; ++l) p[l] = fmaf(hv, fr[l], p[l]);
    }
    __shared__ float ls[4][LBL];
    __shared__ float lg[LBL];
    __shared__ float lse;
#pragma unroll
    for (int l = 0; l < LBL; ++l) {
        float v = p[l];
#pragma unroll
        for (int m = 32; m; m >>= 1) v += __shfl_xor(v, m);
        if ((tid & 63) == 0) ls[tid >> 6][l] = v;
    }
    __syncthreads();
    if (tid < LBL) lg[tid] = ls[0][tid] + ls[1][tid] + ls[2][tid] + ls[3][tid];
    __syncthreads();
    if (tid == 0) {
        float mx = lg[0];
#pragma unroll
        for (int j = 1; j < LBL; ++j) mx = fmaxf(mx, lg[j]);
        float sm = 0.f;
#pragma unroll
        for (int j = 0; j < LBL; ++j) sm += expf(lg[j] - mx);
        lse = mx + logf(sm);
    }
    __syncthreads();
    if (tid < LBL) em[(size_t)tok * LBL + tid] = lg[tid] - lse;
}

// ---------------- CRF: one wave per batch elem, base-2 fast recursion ----------------
__global__ __launch_bounds__(64) void crf_k(
    const float* __restrict__ em, const int* __restrict__ tags,
    const int* __restrict__ mask, const float* __restrict__ sp,
    const float* __restrict__ ep, const float* __restrict__ trans,
    float* __restrict__ partial)
{
    constexpr float LOG2E = 1.4426950408889634f;
    constexpr float LN2   = 0.6931471805599453f;
    int b = blockIdx.x, t = threadIdx.x;
    __shared__ float eml[S * LBL];     // emissions * log2(e)
    __shared__ int mkl[S];
    const float* emb = em + (size_t)b * S * LBL;
    const int* tg = tags + (size_t)b * S;
    const int* mk = mask + (size_t)b * S;

    for (int i = t * 4; i < S * LBL; i += 256) {
        float4 v = *(const float4*)&emb[i];
        v.x *= LOG2E; v.y *= LOG2E; v.z *= LOG2E; v.w *= LOG2E;
        *(float4*)&eml[i] = v;
    }
    *(i32x4*)&mkl[t * 4] = *(const i32x4*)&mk[t * 4];

    // gold-path score (exact f32, base-e)
    int cnt = 0; float ns = 0.f;
    for (int i = t; i < S; i += 64) {
        int m = mk[i];
        cnt += (m != 0);
        if (i >= 1 && m)
            ns += trans[tg[i - 1] * LBL + tg[i]] + emb[(size_t)i * LBL + tg[i]];
    }
#pragma unroll
    for (int m = 32; m; m >>= 1) { cnt += __shfl_xor(cnt, m); ns += __shfl_xor(ns, m); }
    float num = ns + sp[tg[0]] + emb[tg[0]] + ep[tg[cnt - 1]];

    int tt = t < LBL ? t : 0;
    float trc2[LBL];
#pragma unroll
    for (int i = 0; i < LBL; ++i) trc2[i] = trans[i * LBL + tt] * LOG2E;

    __syncthreads();

    float alpha2 = (t < LBL) ? sp[t] * LOG2E + eml[t] : -1e30f;
    for (int step = 1; step < S; ++step) {
        float av[LBL];
#pragma unroll
        for (int i = 0; i < LBL; ++i) av[i] = __shfl(alpha2, i) + trc2[i];
        float mx = av[0];
#pragma unroll
        for (int i = 1; i < LBL; ++i) mx = fmaxf(mx, av[i]);
        float sm = 0.f;
#pragma unroll
        for (int i = 0; i < LBL; ++i) sm += exp2i(av[i] - mx);
        float na = mx + log2i(sm) + eml[step * LBL + tt];
        alpha2 = (mkl[step] && t < LBL) ? na : alpha2;
    }
    float z = (t < LBL) ? alpha2 + ep[t] * LOG2E : -1e30f;
    float mx = z;
#pragma unroll
    for (int m = 8; m; m >>= 1) mx = fmaxf(mx, __shfl_xor(mx, m));
    float sm = exp2i(z - mx);
#pragma unroll
    for (int m = 8; m; m >>= 1) sm += __shfl_xor(sm, m);
    if (t == 0) partial[b] = (mx + log2i(sm)) * LN2 - num;
}

__global__ void finalize_k(const float* __restrict__ partial, float* __restrict__ out) {
    float s = 0.f;
    for (int i = 0; i < BATCH; ++i) s += partial[i];
    out[0] = s;
}

__global__ void sentinel_k(float* out) { out[0] = -12345.0f; }

extern "C" void kernel_launch(void* const* d_in, const int* in_sizes, int n_in,
                              void* d_out, int out_size, void* d_ws, size_t ws_size,
                              hipStream_t stream) {
    (void)in_sizes; (void)n_in; (void)out_size;
    const int* token_ids  = (const int*)d_in[0];
    const int* token_type = (const int*)d_in[1];
    const int* amask      = (const int*)d_in[2];
    const int* y          = (const int*)d_in[3];
    const float* wemb = (const float*)d_in[4];
    const float* pemb = (const float*)d_in[5];
    const float* temb = (const float*)d_in[6];
    const float* eg   = (const float*)d_in[7];
    const float* eb   = (const float*)d_in[8];
    const float* Wq = (const float*)d_in[9];
    const float* bq = (const float*)d_in[10];
    const float* Wk = (const float*)d_in[11];
    const float* bk = (const float*)d_in[12];
    const float* Wv = (const float*)d_in[13];
    const float* bv = (const float*)d_in[14];
    const float* Wo = (const float*)d_in[15];
    const float* bo = (const float*)d_in[16];
    const float* ln1g = (const float*)d_in[17];
    const float* ln1b = (const float*)d_in[18];
    const float* W1 = (const float*)d_in[19];
    const float* b1 = (const float*)d_in[20];
    const float* W2 = (const float*)d_in[21];
    const float* b2 = (const float*)d_in[22];
    const float* ln2g = (const float*)d_in[23];
    const float* ln2b = (const float*)d_in[24];
    const float* fcw = (const float*)d_in[25];
    const float* crf_s = (const float*)d_in[26];
    const float* crf_e = (const float*)d_in[27];
    const float* crf_t = (const float*)d_in[28];

    if (ws_size < WS_FLOATS * sizeof(float)) {
        sentinel_k<<<1, 1, 0, stream>>>((float*)d_out);
        return;
    }

    float* ws = (float*)d_ws;
    float*   hbuf = ws + H_OFF;
    ushortT* hb   = (ushortT*)(ws + HB_OFF);
    ushortT* qb   = (ushortT*)(ws + QB_OFF);   // q base; k = +TOKENS*H; vt = +2*TOKENS*H
    ushortT* kb   = (ushortT*)(ws + KB_OFF);
    ushortT* vt   = (ushortT*)(ws + VT_OFF);
    ushortT* big  = (ushortT*)(ws + BIG_OFF);
    ushortT* wtq  = (ushortT*)(ws + WTQ_OFF);  // [2304][768]
    ushortT* wto  = (ushortT*)(ws + WTO_OFF);
    ushortT* wt1  = (ushortT*)(ws + WT1_OFF);
    ushortT* wt2  = (ushortT*)(ws + WT2_OFF);
    float*   embuf = ws + EM_OFF;
    float*   part  = ws + PART_OFF;
    float*   bqkv  = ws + BQKV_OFF;

    pack_bias_k<<<NLAY * 3, 256, 0, stream>>>(bq, bk, bv, bqkv);
    embed_ln_k<<<TOKENS, 256, 0, stream>>>(token_ids, token_type, wemb, pemb, temb,
                                           eg, eb, hbuf, hb);

    constexpr long long HH = (long long)H * H;
    constexpr long long HF = (long long)H * FF;
    constexpr long long TOKH = (long long)S * H;        // 196608
    constexpr long long ATT_B = (long long)NHD * S * S; // 786432
    constexpr long long ATT_H = (long long)S * S;       // 65536
    constexpr long long VT_B = (long long)NHD * DH * S; // 196608
    constexpr long long VT_H = (long long)DH * S;       // 16384

    dim3 gProj(H / 128, TOKENS / 128, 1);         // 6 x 64
    dim3 gScores(S / 128, S / 128, BATCH * NHD);  // 2 x 2 x 384
    dim3 gPV(1, 1, BATCH * NHD);                  // 256x64 tile covers head

    for (int l = 0; l < NLAY; ++l) {
        transpose_all_k<<<6912, 256, 0, stream>>>(
            Wq + l * HH, Wk + l * HH, Wv + l * HH, Wo + l * HH,
            W1 + l * HF, W2 + l * HF, wtq, wto, wt1, wt2);

        // fused q,k,v projections (deep 8-phase 256^2; q->qb, k->kb, v->vt routing)
        gemm256<5><<<288, 512, 0, stream>>>(
            hb, H, wtq, H, bqkv + (size_t)l * QKVN, qb, H, H, 9);

        // scores = q @ k^T  (per b,h) -> bf16
        gemm_mfma<2,2,4><<<gScores, 256, 0, stream>>>(
            qb, H, TOKH, DH, kb, H, TOKH, DH, nullptr,
            big, S, ATT_B, ATT_H, DH, NHD);

        attn_softmax_bf16_k<<<BATCH * NHD * (S / 16), 256, 0, stream>>>(big, amask);

        // ctx = probs @ v  (per b,h) -> qb as [B,S,NH,DH] bf16
        gemm_mfma<4,1,4><<<gPV, 256, 0, stream>>>(
            big, S, ATT_B, ATT_H, vt, S, VT_B, VT_H, nullptr,
            qb, H, TOKH, DH, S, NHD);

        // attention output projection -> kb (bf16)
        gemm_mfma<2,2,0><<<gProj, 256, 0, stream>>>(
            qb, H, 0, 0, wto, H, 0, 0, bo + l * H, kb, H, 0, 0, H, 1);

        add_ln_k<<<TOKENS, 256, 0, stream>>>(hbuf, kb, ln1g + l * H, ln1b + l * H, hb);

        // ff1 = gelu(h @ W1 + b1) -> big bf16 (deep 8-phase 256^2)
        gemm256<1><<<384, 512, 0, stream>>>(
            hb, H, wt1, H, b1 + (long long)l * FF, big, FF, H, 12);

        // ff2 -> qb (bf16)
        gemm_mfma<2,2,0><<<gProj, 256, 0, stream>>>(
            big, FF, 0, 0, wt2, FF, 0, 0, b2 + l * H, qb, H, 0, 0, FF, 1);

        add_ln_k<<<TOKENS, 256, 0, stream>>>(hbuf, qb, ln2g + l * H, ln2b + l * H, hb);
    }

    logits_k<<<TOKENS, 256, 0, stream>>>(hbuf, fcw, embuf);
    crf_k<<<BATCH, 64, 0, stream>>>(embuf, y, amask, crf_s, crf_e, crf_t, part);
    finalize_k<<<1, 1, 0, stream>>>(part, (float*)d_out);
}

// Round 6
// 3751.620 us; speedup vs baseline: 1.0427x; 1.0427x over previous
//
#include <hip/hip_runtime.h>
#include <math.h>

typedef unsigned short ushortT;
typedef __attribute__((ext_vector_type(4))) float f32x4;
typedef __attribute__((ext_vector_type(4))) unsigned int u32x4;
typedef __attribute__((ext_vector_type(4))) unsigned short u16x4;
typedef __attribute__((ext_vector_type(4))) int i32x4;
typedef __attribute__((ext_vector_type(8))) __bf16 bf16x8;

namespace {
constexpr int S = 256;
constexpr int H = 768;
constexpr int NLAY = 12;
constexpr int NHD = 12;
constexpr int FF = 3072;
constexpr int LBL = 9;
constexpr int DH = 64;
constexpr int BATCH = 32;
constexpr int TOKENS = BATCH * S;      // 8192
constexpr float SCALE = 0.125f;        // 1/sqrt(64)
constexpr int QKVN = 3 * H;            // 2304

// workspace layout (float-slot units)
constexpr size_t H_OFF   = 0;                          // h f32 [8192*768]
constexpr size_t HB_OFF  = H_OFF + (size_t)TOKENS*H;   // h bf16 (half slots)
constexpr size_t QB_OFF  = HB_OFF + (size_t)TOKENS*H/2;  // q / ctx / ff2out bf16
constexpr size_t KB_OFF  = QB_OFF + (size_t)TOKENS*H/2;  // k / attn-out bf16
constexpr size_t VT_OFF  = KB_OFF + (size_t)TOKENS*H/2;  // v^T bf16 [B*NH*DH][S]
constexpr size_t BIG_OFF = VT_OFF + (size_t)TOKENS*H/2;  // scores bf16 == ff1 bf16
constexpr size_t WTQ_OFF = BIG_OFF + (size_t)TOKENS*FF/2;  // Wq^T,Wk^T,Wv^T contiguous
constexpr size_t WTO_OFF = WTQ_OFF + 3*(size_t)H*H/2;
constexpr size_t WT1_OFF = WTO_OFF + (size_t)H*H/2;      // W1^T [3072][768]
constexpr size_t WT2_OFF = WT1_OFF + (size_t)H*FF/2;     // W2^T [768][3072]
constexpr size_t EM_OFF  = WT2_OFF + (size_t)H*FF/2;
constexpr size_t PART_OFF= EM_OFF + (size_t)TOKENS*LBL;
constexpr size_t BQKV_OFF= PART_OFF + 64;                // packed qkv bias [12][2304]
constexpr size_t WS_FLOATS = BQKV_OFF + (size_t)NLAY*QKVN;
}

__device__ __forceinline__ ushortT f2bf(float x) {
    unsigned u = __builtin_bit_cast(unsigned, x);
    u += 0x7fffu + ((u >> 16) & 1u);
    return (ushortT)(u >> 16);
}
__device__ __forceinline__ float bf2f(ushortT h) {
    unsigned u = ((unsigned)h) << 16;
    return __builtin_bit_cast(float, u);
}

__device__ __forceinline__ float exp2i(float x) {
    float r; asm("v_exp_f32 %0, %1" : "=v"(r) : "v"(x)); return r;
}
__device__ __forceinline__ float log2i(float x) {
    float r; asm("v_log_f32 %0, %1" : "=v"(r) : "v"(x)); return r;
}

// tanh-gelu in sigmoid form: 0.5x(1+tanh(u)) == x * sigmoid(2u),
// computed overflow-safe as x / (1 + exp2(-2u*log2e)).
__device__ __forceinline__ float gelu_tanh(float x) {
    float u = 0.7978845608028654f * (x + 0.044715f * x * x * x);
    float t = exp2i(-2.8853900817779268f * u);
    return x / (1.0f + t);
}

// MFMA via compiler builtin: accumulators live in AGPRs (unified file),
// no v_accvgpr shuttling (the inline-asm "+v" form forced VGPR-class C/D
// and the allocator shuttled 128 regs/phase -> R4/R5's 14% MfmaUtil).
__device__ __forceinline__ f32x4 mfma16(u32x4 a, u32x4 b, f32x4 c) {
    return __builtin_amdgcn_mfma_f32_16x16x32_bf16(
        __builtin_bit_cast(bf16x8, a), __builtin_bit_cast(bf16x8, b), c, 0, 0, 0);
}

__device__ __forceinline__ void gload_lds16(const ushortT* g, ushortT* l) {
    __builtin_amdgcn_global_load_lds(
        (const __attribute__((address_space(1))) unsigned int*)g,
        (__attribute__((address_space(3))) unsigned int*)l,
        16, 0, 0);
}

// =====================================================================
// 256x256 8-phase bf16 GEMM — deep pipeline (R5 schedule, R6 builtin MFMA)
// Loads for tile t+1: 6 loads (B + A rows 0-63/128-191) at ph3 of t-1,
// 2 loads (A rows 64-127/192-255) at ph0 of t. Waits vmcnt(8) at ph0/ph1.
// BK=64, 8 waves (2Mx4N), 128 KiB LDS, XOR swizzle (k-chunk ^ row&7) on
// both global source and LDS read.
// MODE: 0 bias bf16 | 1 bias+gelu bf16 | 5 fused-QKV routing
// =====================================================================
template<int MODE>
__global__ __launch_bounds__(512, 2) void gemm256(
    const ushortT* __restrict__ A, int lda,
    const ushortT* __restrict__ Bt, int ldb,
    const float* __restrict__ bias,
    void* __restrict__ Cv, int ldc, int K, int gridN)
{
    __shared__ __align__(16) ushortT sh[65536];   // 128 KiB
    const int tid = threadIdx.x;
    const int wave = tid >> 6, lane = tid & 63;
    const int wm = wave >> 2, wn = wave & 3;
    const int rl = lane & 15, kg = lane >> 4, r7 = lane & 7;

    // XCD-aware swizzle (grid divisible by 8)
    const int nwg = gridDim.x;
    const int cpx = nwg >> 3;
    const int wg = (blockIdx.x & 7) * cpx + (blockIdx.x >> 3);
    const int by = wg / gridN, bx = wg - by * gridN;

    const ushortT* Ab = A + (size_t)by * 256 * lda;
    const ushortT* Bb = Bt + (size_t)bx * 256 * ldb;

    const int kxor8 = ((tid & 7) ^ ((tid >> 3) & 7)) * 8;   // swizzled global k-off
    const int trow = tid >> 3;                               // 0..63 row within round
    const int aoff = (wm * 128 + rl) * 64;
    const int boff = (wn * 64 + rl) * 64;
    const int koff0 = (kg ^ r7) * 8;          // ks=0 swizzled LDS k-off (elems)
    const int koff1 = ((4 | kg) ^ r7) * 8;    // ks=1

    f32x4 acc[8][4];
#pragma unroll
    for (int i = 0; i < 8; ++i)
#pragma unroll
        for (int j = 0; j < 4; ++j) acc[i][j] = (f32x4){0.f, 0.f, 0.f, 0.f};

    const int NT = K >> 6;

#define STAGE_B(RR, KT, NB)                                                     \
    gload_lds16(Bb + (size_t)((RR) * 64 + trow) * ldb + (KT) * 64 + kxor8,      \
                sh + 32768 + (NB) * 16384 + (RR) * 4096 + wave * 512)
#define STAGE_A(ROWBASE, KT, NB)                                                \
    gload_lds16(Ab + (size_t)((ROWBASE) + trow) * lda + (KT) * 64 + kxor8,      \
                sh + (NB) * 16384 + (ROWBASE) * 64 + wave * 512)
#define STAGE6(KT, NB)                                                          \
    STAGE_B(0, KT, NB); STAGE_B(1, KT, NB); STAGE_B(2, KT, NB);                 \
    STAGE_B(3, KT, NB); STAGE_A(0, KT, NB); STAGE_A(128, KT, NB)
#define STAGE2(KT, NB)                                                          \
    STAGE_A(64, KT, NB); STAGE_A(192, KT, NB)
#define LDA_Q(Q, KOFF)                                                          \
    a[0] = *(const u32x4*)(As_ + aoff + (Q) * 4096 +    0 + (KOFF));            \
    a[1] = *(const u32x4*)(As_ + aoff + (Q) * 4096 + 1024 + (KOFF));            \
    a[2] = *(const u32x4*)(As_ + aoff + (Q) * 4096 + 2048 + (KOFF));            \
    a[3] = *(const u32x4*)(As_ + aoff + (Q) * 4096 + 3072 + (KOFF));
#define LDB_(KOFF)                                                              \
    b[0] = *(const u32x4*)(Bs_ + boff +    0 + (KOFF));                         \
    b[1] = *(const u32x4*)(Bs_ + boff + 1024 + (KOFF));                         \
    b[2] = *(const u32x4*)(Bs_ + boff + 2048 + (KOFF));                         \
    b[3] = *(const u32x4*)(Bs_ + boff + 3072 + (KOFF));
#define MFMA_Q(Q)                                                               \
    _Pragma("unroll") for (int mf = 0; mf < 4; ++mf)                            \
    _Pragma("unroll") for (int nf = 0; nf < 4; ++nf)                            \
        acc[(Q) * 4 + mf][nf] = mfma16(a[mf], b[nf], acc[(Q) * 4 + mf][nf]);
#define VM8    asm volatile("s_waitcnt vmcnt(8)" ::: "memory")
#define VM0    asm volatile("s_waitcnt vmcnt(0)" ::: "memory")
#define LG0    asm volatile("s_waitcnt lgkmcnt(0)" ::: "memory")
#define SBAR   __builtin_amdgcn_s_barrier()
#define SCB    __builtin_amdgcn_sched_barrier(0)

    // prologue (FIFO order matters): 6(t0)->buf0, 2(t0)->buf0, 6(t1)->buf1
    STAGE6(0, 0);
    STAGE2(0, 0);
    {
        const int t1 = (NT > 1) ? 1 : 0;
        STAGE6(t1, 1);
    }

    u32x4 a[4], b[4];
    for (int kt = 0; kt < NT; ++kt) {
        const int cur = kt & 1, nb = cur ^ 1;
        const int nx1 = (kt + 1 < NT) ? kt + 1 : kt;   // 2-group source (->nb)
        const int nx2 = (kt + 2 < NT) ? kt + 2 : kt;   // 6-group source (->cur)
        const ushortT* As_ = sh + cur * 16384;
        const ushortT* Bs_ = sh + 32768 + cur * 16384;

        // ---- phase 0: q=0, ks=0 (needs B + A rows 0-63/128-191 of tile kt) ----
        VM8; SBAR; SCB;
        LDA_Q(0, koff0); LDB_(koff0);
        STAGE2(nx1, nb);                  // A hi-half of tile kt+1
        LG0; SCB;
        __builtin_amdgcn_s_setprio(1);
        MFMA_Q(0);
        __builtin_amdgcn_s_setprio(0);

        // ---- phase 1: q=1, ks=0 (needs A rows 64-127/192-255 of tile kt) ----
        VM8; SBAR; SCB;
        LDA_Q(1, koff0);
        LG0; SCB;
        __builtin_amdgcn_s_setprio(1);
        MFMA_Q(1);
        __builtin_amdgcn_s_setprio(0);

        // ---- phase 2: q=0, ks=1 (last read of B and A-loQ of tile kt) ----
        SBAR; SCB;
        LDA_Q(0, koff1); LDB_(koff1);
        LG0; SCB;
        __builtin_amdgcn_s_setprio(1);
        MFMA_Q(0);
        __builtin_amdgcn_s_setprio(0);

        // ---- phase 3: q=1, ks=1; B + A-loQ regions of buffer `cur` are now
        //      dead (all waves past ph2 via this barrier) -> stage tile kt+2 ----
        SBAR; SCB;
        LDA_Q(1, koff1);
        STAGE6(nx2, cur);
        LG0; SCB;
        __builtin_amdgcn_s_setprio(1);
        MFMA_Q(1);
        __builtin_amdgcn_s_setprio(0);
    }
    VM0;   // drain leftover (clamped) stages before exit

    // epilogue
    ushortT* Ch = (ushortT*)Cv;
#pragma unroll
    for (int nf = 0; nf < 4; ++nf) {
        const int gn = bx * 256 + wn * 64 + nf * 16 + rl;
        const float bv = bias[gn];
#pragma unroll
        for (int mi = 0; mi < 8; ++mi) {
            const int gm = by * 256 + wm * 128 + (mi >> 2) * 64 + (mi & 3) * 16
                         + ((lane >> 4) << 2);
            if constexpr (MODE == 5) {
                const int region = gn / H;
                const int col = gn - region * H;
                if (region < 2) {
                    ushortT* o = (ushortT*)Cv + (size_t)region * TOKENS * H;
#pragma unroll
                    for (int r = 0; r < 4; ++r)
                        o[(size_t)(gm + r) * H + col] = f2bf(acc[mi][nf][r] + bv);
                } else {
                    u16x4 o;
#pragma unroll
                    for (int r = 0; r < 4; ++r) o[r] = f2bf(acc[mi][nf][r] + bv);
                    const int b_ = gm >> 8, s0 = gm & 255;
                    const int h_ = col >> 6, dh = col & 63;
                    *(u16x4*)((ushortT*)Cv + 2 * (size_t)TOKENS * H +
                              (((size_t)(b_ * NHD + h_) * DH + dh) << 8) + s0) = o;
                }
            } else {
#pragma unroll
                for (int r = 0; r < 4; ++r) {
                    float x = acc[mi][nf][r] + bv;
                    if constexpr (MODE == 1) x = gelu_tanh(x);
                    Ch[(size_t)(gm + r) * ldc + gn] = f2bf(x);
                }
            }
        }
    }
#undef STAGE_B
#undef STAGE_A
#undef STAGE6
#undef STAGE2
#undef LDA_Q
#undef LDB_
#undef MFMA_Q
#undef VM8
#undef VM0
#undef LG0
#undef SBAR
#undef SCB
}

// ---------------- bf16 MFMA GEMM, double-buffered 2-phase (128^2) ----------------
// MODE: 0 = bf16 out + bias, 4 = bf16 no bias
template<int WM, int WN, int MODE>
__global__ __launch_bounds__(256) void gemm_mfma(
    const ushortT* __restrict__ A, int lda, long long sAo, long long sAi,
    const ushortT* __restrict__ Bt, int ldb, long long sBo, long long sBi,
    const float* __restrict__ bias,
    void* __restrict__ Cv, int ldc, long long sCo, long long sCi,
    int K, int innerN)
{
    constexpr int BM = WM * 64, BN = WN * 64;
    __shared__ __align__(16) ushortT As[2][BM * 32];
    __shared__ __align__(16) ushortT Bs[2][BN * 32];
    const int tid = threadIdx.x;
    const int wave = tid >> 6, lane = tid & 63;
    const int ob = blockIdx.z / innerN, ib = blockIdx.z - ob * innerN;
    const int bm = blockIdx.y * BM, bn = blockIdx.x * BN;
    const ushortT* Ab = A + ob * sAo + ib * sAi + (size_t)bm * lda;
    const ushortT* Bb = Bt + ob * sBo + ib * sBi + (size_t)bn * ldb;
    const int wm = wave / WN, wn = wave - wm * WN;

    const int lrow = lane >> 2;
    const int lk16 = (lane & 3) * 8;
    const int rl = lane & 15;
    const int kg = (lane >> 4) * 8;

    f32x4 acc[4][4];
#pragma unroll
    for (int i = 0; i < 4; ++i)
#pragma unroll
        for (int j = 0; j < 4; ++j) acc[i][j] = (f32x4){0.f, 0.f, 0.f, 0.f};

    auto stage = [&](int buf, int k0) {
#pragma unroll
        for (int j = 0; j < WM; ++j) {
            int chunk = j * 4 + wave;
            gload_lds16(Ab + (size_t)(chunk * 16 + lrow) * lda + k0 + lk16,
                        &As[buf][chunk * 512]);
        }
#pragma unroll
        for (int j = 0; j < WN; ++j) {
            int chunk = j * 4 + wave;
            gload_lds16(Bb + (size_t)(chunk * 16 + lrow) * ldb + k0 + lk16,
                        &Bs[buf][chunk * 512]);
        }
    };

    stage(0, 0);
    __syncthreads();
    const int nt = K >> 5;
    int cur = 0;
    for (int t = 0; t < nt; ++t) {
        if (t + 1 < nt) stage(cur ^ 1, (t + 1) << 5);
        u32x4 a[4], b[4];
#pragma unroll
        for (int mf = 0; mf < 4; ++mf)
            a[mf] = *(const u32x4*)&As[cur][(wm * 64 + mf * 16 + rl) * 32 + kg];
#pragma unroll
        for (int nf = 0; nf < 4; ++nf)
            b[nf] = *(const u32x4*)&Bs[cur][(wn * 64 + nf * 16 + rl) * 32 + kg];
#pragma unroll
        for (int mf = 0; mf < 4; ++mf)
#pragma unroll
            for (int nf = 0; nf < 4; ++nf)
                acc[mf][nf] = mfma16(a[mf], b[nf], acc[mf][nf]);
        __syncthreads();
        cur ^= 1;
    }

    ushortT* Ch = (ushortT*)Cv + ob * sCo + ib * sCi;
#pragma unroll
    for (int nf = 0; nf < 4; ++nf) {
        int gn = bn + wn * 64 + nf * 16 + rl;
        float bv = 0.f;
        if constexpr (MODE == 0) bv = bias[gn];
#pragma unroll
        for (int mf = 0; mf < 4; ++mf) {
            int gm = bm + wm * 64 + mf * 16 + ((lane >> 4) << 2);
#pragma unroll
            for (int r = 0; r < 4; ++r) {
                float x = acc[mf][nf][r] + bv;
                Ch[(size_t)(gm + r) * ldc + gn] = f2bf(x);
            }
        }
    }
}

// ---------------- all 6 weight transposes of one layer, one dispatch ----------------
__global__ __launch_bounds__(256) void transpose_all_k(
    const float* __restrict__ Wq, const float* __restrict__ Wk,
    const float* __restrict__ Wv, const float* __restrict__ Wo,
    const float* __restrict__ W1, const float* __restrict__ W2,
    ushortT* __restrict__ wtqkv, ushortT* __restrict__ wto,
    ushortT* __restrict__ wt1, ushortT* __restrict__ wt2)
{
    int idx = blockIdx.x;
    const float* W; ushortT* WT; int R, C, tr, tc;
    if (idx < 2304) {
        int mat = idx / 576, t = idx - mat * 576;
        tr = t / 24; tc = t - tr * 24; R = 768; C = 768;
        W = mat == 0 ? Wq : mat == 1 ? Wk : mat == 2 ? Wv : Wo;
        WT = mat < 3 ? wtqkv + (size_t)mat * 768 * 768 : wto;
    } else if (idx < 4608) {
        int t = idx - 2304; tr = t / 96; tc = t - tr * 96;
        R = 768; C = 3072; W = W1; WT = wt1;
    } else {
        int t = idx - 4608; tr = t / 24; tc = t - tr * 24;
        R = 3072; C = 768; W = W2; WT = wt2;
    }
    int r0 = tr * 32, c0 = tc * 32;
    __shared__ float tl[32][33];
    int trd = threadIdx.x >> 3;
    int tc4 = (threadIdx.x & 7) * 4;
    const float4 v = *(const float4*)(W + (size_t)(r0 + trd) * C + c0 + tc4);
    tl[trd][tc4 + 0] = v.x; tl[trd][tc4 + 1] = v.y;
    tl[trd][tc4 + 2] = v.z; tl[trd][tc4 + 3] = v.w;
    __syncthreads();
    u16x4 o;
#pragma unroll
    for (int q = 0; q < 4; ++q) o[q] = f2bf(tl[tc4 + q][trd]);
    *(u16x4*)(WT + (size_t)(c0 + trd) * R + r0 + tc4) = o;
}

// ---------------- pack qkv biases -> [NLAY][2304] ----------------
__global__ __launch_bounds__(256) void pack_bias_k(
    const float* __restrict__ bq, const float* __restrict__ bk,
    const float* __restrict__ bv, float* __restrict__ out)
{
    int l = blockIdx.x / 3, r = blockIdx.x - (blockIdx.x / 3) * 3;
    const float* src = r == 0 ? bq : r == 1 ? bk : bv;
#pragma unroll
    for (int j = 0; j < 3; ++j) {
        int d = threadIdx.x + 256 * j;
        out[(size_t)l * QKVN + r * H + d] = src[(size_t)l * H + d];
    }
}

// ---------------- block reduce helper ----------------
__device__ inline void blk_reduce2(float& s, float& ss, float* red) {
#pragma unroll
    for (int m = 32; m; m >>= 1) { s += __shfl_xor(s, m); ss += __shfl_xor(ss, m); }
    int w = threadIdx.x >> 6;
    if ((threadIdx.x & 63) == 0) { red[w] = s; red[4 + w] = ss; }
    __syncthreads();
    s = red[0] + red[1] + red[2] + red[3];
    ss = red[4] + red[5] + red[6] + red[7];
}

// ---------------- embeddings + LN (emit f32 + bf16) ----------------
__global__ __launch_bounds__(256) void embed_ln_k(
    const int* __restrict__ ids, const int* __restrict__ tts,
    const float* __restrict__ wemb, const float* __restrict__ pemb,
    const float* __restrict__ temb, const float* __restrict__ g,
    const float* __restrict__ bp, float* __restrict__ h, ushortT* __restrict__ hb)
{
    int tok = blockIdx.x, tid = threadIdx.x;
    int spos = tok & (S - 1);
    int id = ids[tok], tt = tts[tok];
    const float* wr = wemb + (size_t)id * H;
    const float* pr = pemb + (size_t)spos * H;
    const float* tr = temb + (size_t)tt * H;
    float x[3]; float s = 0.f, ss = 0.f;
#pragma unroll
    for (int j = 0; j < 3; ++j) {
        int d = tid + 256 * j;
        x[j] = wr[d] + pr[d] + tr[d];
        s += x[j]; ss += x[j] * x[j];
    }
    __shared__ float red[8];
    blk_reduce2(s, ss, red);
    float mu = s * (1.f / H);
    float var = ss * (1.f / H) - mu * mu;
    float rs = rsqrtf(var + 1e-12f);
#pragma unroll
    for (int j = 0; j < 3; ++j) {
        int d = tid + 256 * j;
        float y = (x[j] - mu) * rs * g[d] + bp[d];
        h[(size_t)tok * H + d] = y;
        hb[(size_t)tok * H + d] = f2bf(y);
    }
}

// ---------------- residual add (bf16 operand) + LN, in place on h ----------------
__global__ __launch_bounds__(256) void add_ln_k(
    float* __restrict__ h, const ushortT* __restrict__ add,
    const float* __restrict__ g, const float* __restrict__ bp,
    ushortT* __restrict__ hb)
{
    int tok = blockIdx.x, tid = threadIdx.x;
    float x[3]; float s = 0.f, ss = 0.f;
#pragma unroll
    for (int j = 0; j < 3; ++j) {
        int d = tid + 256 * j;
        x[j] = h[(size_t)tok * H + d] + bf2f(add[(size_t)tok * H + d]);
        s += x[j]; ss += x[j] * x[j];
    }
    __shared__ float red[8];
    blk_reduce2(s, ss, red);
    float mu = s * (1.f / H);
    float var = ss * (1.f / H) - mu * mu;
    float rs = rsqrtf(var + 1e-12f);
#pragma unroll
    for (int j = 0; j < 3; ++j) {
        int d = tid + 256 * j;
        float y = (x[j] - mu) * rs * g[d] + bp[d];
        h[(size_t)tok * H + d] = y;
        hb[(size_t)tok * H + d] = f2bf(y);
    }
}

// ---------------- scale + mask + softmax on bf16 scores (in place) ----------------
__global__ __launch_bounds__(256) void attn_softmax_bf16_k(
    ushortT* __restrict__ att, const int* __restrict__ mask)
{
    int blk = blockIdx.x, tid = threadIdx.x;
    int bh = blk >> 4;
    int r0 = (blk & 15) * 16;
    int b = bh / NHD;
    int r = tid >> 4, c0 = (tid & 15) * 16;
    ushortT* rp = att + ((size_t)bh * S + r0 + r) * S;
    const int* mrow = mask + (size_t)b * S;

    u32x4 x0 = *(const u32x4*)(rp + c0);
    u32x4 x1 = *(const u32x4*)(rp + c0 + 8);
    unsigned w[8];
    *(u32x4*)&w[0] = x0; *(u32x4*)&w[4] = x1;
    float v[16];
#pragma unroll
    for (int i = 0; i < 8; ++i) {
        v[2 * i]     = bf2f((ushortT)(w[i] & 0xffffu));
        v[2 * i + 1] = bf2f((ushortT)(w[i] >> 16));
    }
#pragma unroll
    for (int j = 0; j < 16; ++j)
        v[j] = v[j] * SCALE + (mrow[c0 + j] ? 0.f : -1e9f);
    float mx = -1e30f;
#pragma unroll
    for (int j = 0; j < 16; ++j) mx = fmaxf(mx, v[j]);
#pragma unroll
    for (int m = 8; m; m >>= 1) mx = fmaxf(mx, __shfl_xor(mx, m));
    float sum = 0.f;
#pragma unroll
    for (int j = 0; j < 16; ++j) { v[j] = expf(v[j] - mx); sum += v[j]; }
#pragma unroll
    for (int m = 8; m; m >>= 1) sum += __shfl_xor(sum, m);
    float inv = 1.f / sum;
#pragma unroll
    for (int i = 0; i < 8; ++i)
        w[i] = (unsigned)f2bf(v[2 * i] * inv) |
               ((unsigned)f2bf(v[2 * i + 1] * inv) << 16);
    *(u32x4*)(rp + c0) = *(u32x4*)&w[0];
    *(u32x4*)(rp + c0 + 8) = *(u32x4*)&w[4];
}

// ---------------- logits + log_softmax over 9 labels (f32 exact) ----------------
__global__ __launch_bounds__(256) void logits_k(
    const float* __restrict__ h, const float* __restrict__ fcw, float* __restrict__ em)
{
    int tok = blockIdx.x, tid = threadIdx.x;
    float p[LBL];
#pragma unroll
    for (int l = 0; l < LBL; ++l) p[l] = 0.f;
    const float* hr = h + (size_t)tok * H;
#pragma unroll
    for (int j = 0; j < 3; ++j) {
        int d = tid + 256 * j;
        float hv = hr[d];
        const float* fr = fcw + (size_t)d * LBL;
#pragma unroll
        for (int l = 0; l < LBL; ++l) p[l] = fmaf(hv, fr[l], p[l]);
    }
    __shared__ float ls[4][LBL];
    __shared__ float lg[LBL];
    __shared__ float lse;
#pragma unroll
    for (int l = 0; l < LBL; ++l) {
        float v = p[l];
#pragma unroll
        for (int m = 32; m; m >>= 1) v += __shfl_xor(v, m);
        if ((tid & 63) == 0) ls[tid >> 6][l] = v;
    }
    __syncthreads();
    if (tid < LBL) lg[tid] = ls[0][tid] + ls[1][tid] + ls[2][tid] + ls[3][tid];
    __syncthreads();
    if (tid == 0) {
        float mx = lg[0];
#pragma unroll
        for (int j = 1; j < LBL; ++j) mx = fmaxf(mx, lg[j]);
        float sm = 0.f;
#pragma unroll
        for (int j = 0; j < LBL; ++j) sm += expf(lg[j] - mx);
        lse = mx + logf(sm);
    }
    __syncthreads();
    if (tid < LBL) em[(size_t)tok * LBL + tid] = lg[tid] - lse;
}

// ---------------- CRF: one wave per batch elem, base-2 fast recursion ----------------
__global__ __launch_bounds__(64) void crf_k(
    const float* __restrict__ em, const int* __restrict__ tags,
    const int* __restrict__ mask, const float* __restrict__ sp,
    const float* __restrict__ ep, const float* __restrict__ trans,
    float* __restrict__ partial)
{
    constexpr float LOG2E = 1.4426950408889634f;
    constexpr float LN2   = 0.6931471805599453f;
    int b = blockIdx.x, t = threadIdx.x;
    __shared__ float eml[S * LBL];     // emissions * log2(e)
    __shared__ int mkl[S];
    const float* emb = em + (size_t)b * S * LBL;
    const int* tg = tags + (size_t)b * S;
    const int* mk = mask + (size_t)b * S;

    for (int i = t * 4; i < S * LBL; i += 256) {
        float4 v = *(const float4*)&emb[i];
        v.x *= LOG2E; v.y *= LOG2E; v.z *= LOG2E; v.w *= LOG2E;
        *(float4*)&eml[i] = v;
    }
    *(i32x4*)&mkl[t * 4] = *(const i32x4*)&mk[t * 4];

    // gold-path score (exact f32, base-e)
    int cnt = 0; float ns = 0.f;
    for (int i = t; i < S; i += 64) {
        int m = mk[i];
        cnt += (m != 0);
        if (i >= 1 && m)
            ns += trans[tg[i - 1] * LBL + tg[i]] + emb[(size_t)i * LBL + tg[i]];
    }
#pragma unroll
    for (int m = 32; m; m >>= 1) { cnt += __shfl_xor(cnt, m); ns += __shfl_xor(ns, m); }
    float num = ns + sp[tg[0]] + emb[tg[0]] + ep[tg[cnt - 1]];

    int tt = t < LBL ? t : 0;
    float trc2[LBL];
#pragma unroll
    for (int i = 0; i < LBL; ++i) trc2[i] = trans[i * LBL + tt] * LOG2E;

    __syncthreads();

    float alpha2 = (t < LBL) ? sp[t] * LOG2E + eml[t] : -1e30f;
    for (int step = 1; step < S; ++step) {
        float av[LBL];
#pragma unroll
        for (int i = 0; i < LBL; ++i) av[i] = __shfl(alpha2, i) + trc2[i];
        float mx = av[0];
#pragma unroll
        for (int i = 1; i < LBL; ++i) mx = fmaxf(mx, av[i]);
        float sm = 0.f;
#pragma unroll
        for (int i = 0; i < LBL; ++i) sm += exp2i(av[i] - mx);
        float na = mx + log2i(sm) + eml[step * LBL + tt];
        alpha2 = (mkl[step] && t < LBL) ? na : alpha2;
    }
    float z = (t < LBL) ? alpha2 + ep[t] * LOG2E : -1e30f;
    float mx = z;
#pragma unroll
    for (int m = 8; m; m >>= 1) mx = fmaxf(mx, __shfl_xor(mx, m));
    float sm = exp2i(z - mx);
#pragma unroll
    for (int m = 8; m; m >>= 1) sm += __shfl_xor(sm, m);
    if (t == 0) partial[b] = (mx + log2i(sm)) * LN2 - num;
}

__global__ void finalize_k(const float* __restrict__ partial, float* __restrict__ out) {
    float s = 0.f;
    for (int i = 0; i < BATCH; ++i) s += partial[i];
    out[0] = s;
}

__global__ void sentinel_k(float* out) { out[0] = -12345.0f; }

extern "C" void kernel_launch(void* const* d_in, const int* in_sizes, int n_in,
                              void* d_out, int out_size, void* d_ws, size_t ws_size,
                              hipStream_t stream) {
    (void)in_sizes; (void)n_in; (void)out_size;
    const int* token_ids  = (const int*)d_in[0];
    const int* token_type = (const int*)d_in[1];
    const int* amask      = (const int*)d_in[2];
    const int* y          = (const int*)d_in[3];
    const float* wemb = (const float*)d_in[4];
    const float* pemb = (const float*)d_in[5];
    const float* temb = (const float*)d_in[6];
    const float* eg   = (const float*)d_in[7];
    const float* eb   = (const float*)d_in[8];
    const float* Wq = (const float*)d_in[9];
    const float* bq = (const float*)d_in[10];
    const float* Wk = (const float*)d_in[11];
    const float* bk = (const float*)d_in[12];
    const float* Wv = (const float*)d_in[13];
    const float* bv = (const float*)d_in[14];
    const float* Wo = (const float*)d_in[15];
    const float* bo = (const float*)d_in[16];
    const float* ln1g = (const float*)d_in[17];
    const float* ln1b = (const float*)d_in[18];
    const float* W1 = (const float*)d_in[19];
    const float* b1 = (const float*)d_in[20];
    const float* W2 = (const float*)d_in[21];
    const float* b2 = (const float*)d_in[22];
    const float* ln2g = (const float*)d_in[23];
    const float* ln2b = (const float*)d_in[24];
    const float* fcw = (const float*)d_in[25];
    const float* crf_s = (const float*)d_in[26];
    const float* crf_e = (const float*)d_in[27];
    const float* crf_t = (const float*)d_in[28];

    if (ws_size < WS_FLOATS * sizeof(float)) {
        sentinel_k<<<1, 1, 0, stream>>>((float*)d_out);
        return;
    }

    float* ws = (float*)d_ws;
    float*   hbuf = ws + H_OFF;
    ushortT* hb   = (ushortT*)(ws + HB_OFF);
    ushortT* qb   = (ushortT*)(ws + QB_OFF);   // q base; k = +TOKENS*H; vt = +2*TOKENS*H
    ushortT* kb   = (ushortT*)(ws + KB_OFF);
    ushortT* vt   = (ushortT*)(ws + VT_OFF);
    ushortT* big  = (ushortT*)(ws + BIG_OFF);
    ushortT* wtq  = (ushortT*)(ws + WTQ_OFF);  // [2304][768]
    ushortT* wto  = (ushortT*)(ws + WTO_OFF);
    ushortT* wt1  = (ushortT*)(ws + WT1_OFF);
    ushortT* wt2  = (ushortT*)(ws + WT2_OFF);
    float*   embuf = ws + EM_OFF;
    float*   part  = ws + PART_OFF;
    float*   bqkv  = ws + BQKV_OFF;

    pack_bias_k<<<NLAY * 3, 256, 0, stream>>>(bq, bk, bv, bqkv);
    embed_ln_k<<<TOKENS, 256, 0, stream>>>(token_ids, token_type, wemb, pemb, temb,
                                           eg, eb, hbuf, hb);

    constexpr long long HH = (long long)H * H;
    constexpr long long HF = (long long)H * FF;
    constexpr long long TOKH = (long long)S * H;        // 196608
    constexpr long long ATT_B = (long long)NHD * S * S; // 786432
    constexpr long long ATT_H = (long long)S * S;       // 65536
    constexpr long long VT_B = (long long)NHD * DH * S; // 196608
    constexpr long long VT_H = (long long)DH * S;       // 16384

    dim3 gProj(H / 128, TOKENS / 128, 1);         // 6 x 64
    dim3 gScores(S / 128, S / 128, BATCH * NHD);  // 2 x 2 x 384
    dim3 gPV(1, 1, BATCH * NHD);                  // 256x64 tile covers head

    for (int l = 0; l < NLAY; ++l) {
        transpose_all_k<<<6912, 256, 0, stream>>>(
            Wq + l * HH, Wk + l * HH, Wv + l * HH, Wo + l * HH,
            W1 + l * HF, W2 + l * HF, wtq, wto, wt1, wt2);

        // fused q,k,v projections (deep 8-phase 256^2; q->qb, k->kb, v->vt routing)
        gemm256<5><<<288, 512, 0, stream>>>(
            hb, H, wtq, H, bqkv + (size_t)l * QKVN, qb, H, H, 9);

        // scores = q @ k^T  (per b,h) -> bf16
        gemm_mfma<2,2,4><<<gScores, 256, 0, stream>>>(
            qb, H, TOKH, DH, kb, H, TOKH, DH, nullptr,
            big, S, ATT_B, ATT_H, DH, NHD);

        attn_softmax_bf16_k<<<BATCH * NHD * (S / 16), 256, 0, stream>>>(big, amask);

        // ctx = probs @ v  (per b,h) -> qb as [B,S,NH,DH] bf16
        gemm_mfma<4,1,4><<<gPV, 256, 0, stream>>>(
            big, S, ATT_B, ATT_H, vt, S, VT_B, VT_H, nullptr,
            qb, H, TOKH, DH, S, NHD);

        // attention output projection -> kb (bf16)
        gemm_mfma<2,2,0><<<gProj, 256, 0, stream>>>(
            qb, H, 0, 0, wto, H, 0, 0, bo + l * H, kb, H, 0, 0, H, 1);

        add_ln_k<<<TOKENS, 256, 0, stream>>>(hbuf, kb, ln1g + l * H, ln1b + l * H, hb);

        // ff1 = gelu(h @ W1 + b1) -> big bf16 (deep 8-phase 256^2)
        gemm256<1><<<384, 512, 0, stream>>>(
            hb, H, wt1, H, b1 + (long long)l * FF, big, FF, H, 12);

        // ff2 -> qb (bf16)
        gemm_mfma<2,2,0><<<gProj, 256, 0, stream>>>(
            big, FF, 0, 0, wt2, FF, 0, 0, b2 + l * H, qb, H, 0, 0, FF, 1);

        add_ln_k<<<TOKENS, 256, 0, stream>>>(hbuf, qb, ln2g + l * H, ln2b + l * H, hb);
    }

    logits_k<<<TOKENS, 256, 0, stream>>>(hbuf, fcw, embuf);
    crf_k<<<BATCH, 64, 0, stream>>>(embuf, y, amask, crf_s, crf_e, crf_t, part);
    finalize_k<<<1, 1, 0, stream>>>(part, (float*)d_out);
}